// Round 3
// baseline (303.324 us; speedup 1.0000x reference)
//
#include <hip/hip_runtime.h>

// RoIMaskAlignAvg: features (B=2, C=256, H=200, W=272) fp32, rois (N=256, 5)
// -> out (256, 256, 14, 14) fp32.
// out[ah,aw] = sum over 4x4 window (stride 2) of a 30x30 bilinear sample grid,
// with the 1/16 scale folded into the bilinear weights (0.25 into wx, 0.25 into wy).
//
// Register-only pipeline (no LDS): lanes 0..31 sample row 2p, lanes 32..63 row
// 2p+1 (x index ix = lane&31, samples 0..29 valid). Horizontal 4-window sums via
// shfl_xor(1)+shfl_down(2); cross-half row-pair via shfl_xor(32); vertical 4-sum
// via prev-pass register. Rows stored directly to global from 14 writer lanes.
// Each wave processes 4 consecutive channels, sharing y-metadata/weights/offsets.

#define C_  256
#define H_  200
#define W_  272
#define CPW 4          // channels per wave
#define CPB (CPW * 4)  // 16 channels per block

__global__ __launch_bounds__(256)
void roi_mask_align_avg_kernel(const float* __restrict__ feat,
                               const float* __restrict__ rois,
                               float* __restrict__ out) {
    const int tid  = threadIdx.x;
    const int wave = tid >> 6;
    const int lane = tid & 63;
    const int ix   = lane & 31;    // sample x index (0..29 used)
    const int half = lane >> 5;    // row parity within a pass

    // XCD-aware swizzle: XCD (p%8) streams a fixed channel slice over all rois.
    // grid = 4096: p = xcd + 8*(n + 256*cgi), cgi in 0..1
    const int p   = blockIdx.x;
    const int xcd = p & 7;
    const int q   = p >> 3;
    const int n   = q & 255;
    const int cgi = q >> 8;                 // 0..1
    const int cg  = cgi * 8 + xcd;          // 0..15
    const int c0  = cg * CPB + wave * CPW;  // this wave's first channel

    // --- per-roi geometry (reference fp op order) ---
    const float r0f = rois[n * 5 + 0];
    const float x1s = rois[n * 5 + 1] * 0.25f;
    const float y1s = rois[n * 5 + 2] * 0.25f;
    const float x2s = rois[n * 5 + 3] * 0.25f;
    const float y2s = rois[n * 5 + 4] * 0.25f;
    const int   b   = (int)r0f;

    const float cx = 0.5f * (x1s + x2s), cy = 0.5f * (y1s + y2s);
    const float hw = 0.5f * (x2s - x1s), hh = 0.5f * (y2s - y1s);
    const float x1 = cx - hw, x2 = cx + hw;
    const float y1 = cy - hh, y2 = cy + hh;
    const float roi_w = fmaxf(x2 - x1, 1.0f);
    const float roi_h = fmaxf(y2 - y1, 1.0f);
    const float sub_w = roi_w * (1.0f / 15.0f) * 0.5f;
    const float sub_h = roi_h * (1.0f / 15.0f) * 0.5f;

    // --- x metadata in registers (1/4 of the 1/16 scale folded into wx) ---
    const float sx  = x1 + ((float)ix + 0.5f) * sub_w;
    const float vmx = ((sx > -1.0f) && (sx < (float)W_)) ? 0.25f : 0.0f;
    const float ccx = fminf(fmaxf(sx, 0.0f), (float)(W_ - 1));
    const float lox = floorf(ccx);
    const int   xl  = (int)lox;
    const int   xh  = min(xl + 1, W_ - 1);
    const float fxv = ccx - lox;
    const float wx0 = (1.0f - fxv) * vmx;
    const float wx1 = fxv * vmx;

    const size_t HW = (size_t)H_ * W_;
    const float* __restrict__ fp0 = feat + ((size_t)b * C_ + c0) * HW;
    float* __restrict__ op0 = out + ((size_t)n * C_ + c0) * 196;

    const bool writer = (half == 0) && ((ix & 1) == 0) && (ix < 28);
    const int  ocol   = ix >> 1;   // aw

    float prev[CPW];
    #pragma unroll
    for (int k = 0; k < CPW; ++k) prev[k] = 0.0f;

    for (int ps = 0; ps < 15; ++ps) {
        // --- y metadata for this pass's row (shared across 4 channels) ---
        const int   iy  = 2 * ps + half;
        const float sy  = y1 + ((float)iy + 0.5f) * sub_h;
        const float vmy = ((sy > -1.0f) && (sy < (float)H_)) ? 0.25f : 0.0f;
        const float ccy = fminf(fmaxf(sy, 0.0f), (float)(H_ - 1));
        const float loy = floorf(ccy);
        const int   yl  = (int)loy;
        const int   yh  = min(yl + 1, H_ - 1);
        const float fyv = ccy - loy;
        const float wy0 = (1.0f - fyv) * vmy;
        const float wy1 = fyv * vmy;

        const float w00 = wy0 * wx0, w01 = wy0 * wx1;
        const float w10 = wy1 * wx0, w11 = wy1 * wx1;
        const int o00 = yl * W_ + xl, o01 = yl * W_ + xh;
        const int o10 = yh * W_ + xl, o11 = yh * W_ + xh;

        #pragma unroll
        for (int k = 0; k < CPW; ++k) {
            const float* __restrict__ fpk = fp0 + (size_t)k * HW;
            const float v = fpk[o00] * w00 + fpk[o01] * w01
                          + fpk[o10] * w10 + fpk[o11] * w11;
            // horizontal 4-window sum at even ix: v(ix)+v(ix+1)+v(ix+2)+v(ix+3)
            const float s1 = v  + __shfl_xor(v, 1);
            const float hs = s1 + __shfl_down(s1, 2);
            // vertical row-pair: row 2p + row 2p+1
            const float pr = hs + __shfl_xor(hs, 32);
            // out row (ps-1) = pair(ps-1) + pair(ps)
            if (ps > 0 && writer) {
                op0[(size_t)k * 196 + (ps - 1) * 14 + ocol] = prev[k] + pr;
            }
            prev[k] = pr;
        }
    }
}

extern "C" void kernel_launch(void* const* d_in, const int* in_sizes, int n_in,
                              void* d_out, int out_size, void* d_ws, size_t ws_size,
                              hipStream_t stream) {
    const float* feat = (const float*)d_in[0];
    const float* rois = (const float*)d_in[1];
    float* out = (float*)d_out;
    const int grid = 256 * (C_ / CPB);   // 4096 blocks
    roi_mask_align_avg_kernel<<<grid, 256, 0, stream>>>(feat, rois, out);
}

// Round 4
// 279.422 us; speedup vs baseline: 1.0855x; 1.0855x over previous
//
#include <hip/hip_runtime.h>

// RoIMaskAlignAvg: features (B=2, C=256, H=200, W=272) fp32, rois (N=256, 5)
// -> out (256, 256, 14, 14) fp32.
// out[ah,aw] = sum over 4x4 window (stride 2) of a 30x30 bilinear sample grid,
// with the 1/16 scale folded into the bilinear weights (0.25 into wx, 0.25 into wy).
//
// Register pipeline: lanes 0..31 sample row 2p, lanes 32..63 row 2p+1 (x index
// ix = lane&31, samples 0..29 valid). Horizontal 4-window sums via
// shfl_xor(1)+shfl_down(2); cross-half row-pair via shfl_xor(32); vertical 4-sum
// via prev-pass register. Each wave processes 4 consecutive channels, sharing
// y-metadata/weights/gather-offsets across channels (gather offsets are lane-
// VGPRs reused for all 4 channels; channel base pointers are wave-uniform SGPRs).
//
// Store fix vs r3: output rows staged in per-wave LDS (784 floats), then one
// coalesced 64-lane store pass (contiguous 4-channel 784-float span) -> each
// output cacheline written exactly once, no write-allocate RMW traffic.
// Wave-synchronous LDS use: no __syncthreads anywhere.

#define C_  256
#define H_  200
#define W_  272
#define CPW 4          // channels per wave
#define CPB (CPW * 4)  // 16 channels per block

__global__ __launch_bounds__(256)
void roi_mask_align_avg_kernel(const float* __restrict__ feat,
                               const float* __restrict__ rois,
                               float* __restrict__ out) {
    __shared__ float Obuf[4][CPW * 196];   // 4 waves * 784 floats = 12.25 KB

    const int tid  = threadIdx.x;
    const int wave = tid >> 6;
    const int lane = tid & 63;
    const int ix   = lane & 31;    // sample x index (0..29 used)
    const int half = lane >> 5;    // row parity within a pass

    // XCD-aware swizzle: XCD (p%8) streams a fixed channel slice over all rois.
    const int p   = blockIdx.x;
    const int xcd = p & 7;
    const int q   = p >> 3;
    const int n   = q & 255;
    const int cgi = q >> 8;                 // 0..1
    const int cg  = cgi * 8 + xcd;          // 0..15
    const int c0  = cg * CPB + wave * CPW;  // this wave's first channel

    // --- per-roi geometry (reference fp op order) ---
    const float r0f = rois[n * 5 + 0];
    const float x1s = rois[n * 5 + 1] * 0.25f;
    const float y1s = rois[n * 5 + 2] * 0.25f;
    const float x2s = rois[n * 5 + 3] * 0.25f;
    const float y2s = rois[n * 5 + 4] * 0.25f;
    const int   b   = (int)r0f;

    const float cx = 0.5f * (x1s + x2s), cy = 0.5f * (y1s + y2s);
    const float hw = 0.5f * (x2s - x1s), hh = 0.5f * (y2s - y1s);
    const float x1 = cx - hw, x2 = cx + hw;
    const float y1 = cy - hh, y2 = cy + hh;
    const float roi_w = fmaxf(x2 - x1, 1.0f);
    const float roi_h = fmaxf(y2 - y1, 1.0f);
    const float sub_w = roi_w * (1.0f / 15.0f) * 0.5f;
    const float sub_h = roi_h * (1.0f / 15.0f) * 0.5f;

    // --- x metadata in registers (1/4 of the 1/16 scale folded into wx) ---
    const float sx  = x1 + ((float)ix + 0.5f) * sub_w;
    const float vmx = ((sx > -1.0f) && (sx < (float)W_)) ? 0.25f : 0.0f;
    const float ccx = fminf(fmaxf(sx, 0.0f), (float)(W_ - 1));
    const float lox = floorf(ccx);
    const int   xl  = (int)lox;
    const int   xh  = min(xl + 1, W_ - 1);
    const float fxv = ccx - lox;
    const float wx0 = (1.0f - fxv) * vmx;
    const float wx1 = fxv * vmx;

    const size_t HW = (size_t)H_ * W_;
    const float* __restrict__ fp0 = feat + ((size_t)b * C_ + c0) * HW;

    const bool writer = (half == 0) && ((ix & 1) == 0) && (ix < 28);
    const int  ocol   = ix >> 1;           // aw
    float* __restrict__ Ow = Obuf[wave];

    float prev[CPW];
    #pragma unroll
    for (int k = 0; k < CPW; ++k) prev[k] = 0.0f;

    for (int ps = 0; ps < 15; ++ps) {
        // --- y metadata for this pass's row (shared across 4 channels) ---
        const int   iy  = 2 * ps + half;
        const float sy  = y1 + ((float)iy + 0.5f) * sub_h;
        const float vmy = ((sy > -1.0f) && (sy < (float)H_)) ? 0.25f : 0.0f;
        const float ccy = fminf(fmaxf(sy, 0.0f), (float)(H_ - 1));
        const float loy = floorf(ccy);
        const int   yl  = (int)loy;
        const int   yh  = min(yl + 1, H_ - 1);
        const float fyv = ccy - loy;
        const float wy0 = (1.0f - fyv) * vmy;
        const float wy1 = fyv * vmy;

        const float w00 = wy0 * wx0, w01 = wy0 * wx1;
        const float w10 = wy1 * wx0, w11 = wy1 * wx1;
        const int o00 = yl * W_ + xl, o01 = yl * W_ + xh;
        const int o10 = yh * W_ + xl, o11 = yh * W_ + xh;

        #pragma unroll
        for (int k = 0; k < CPW; ++k) {
            const float* __restrict__ fpk = fp0 + (size_t)k * HW;
            const float v = fpk[o00] * w00 + fpk[o01] * w01
                          + fpk[o10] * w10 + fpk[o11] * w11;
            // horizontal 4-window sum at even ix: v(ix)+v(ix+1)+v(ix+2)+v(ix+3)
            const float s1 = v  + __shfl_xor(v, 1);
            const float hs = s1 + __shfl_down(s1, 2);
            // vertical row-pair: row 2p + row 2p+1
            const float pr = hs + __shfl_xor(hs, 32);
            // out row (ps-1) = pair(ps-1) + pair(ps); stage in LDS
            if (ps > 0 && writer) {
                Ow[k * 196 + (ps - 1) * 14 + ocol] = prev[k] + pr;
            }
            prev[k] = pr;
        }
    }

    // --- coalesced store: this wave's 4 consecutive channels are contiguous ---
    // wave-synchronous (same wave wrote Ow) -> no barrier needed
    float* __restrict__ op0 = out + ((size_t)n * C_ + c0) * 196;
    #pragma unroll
    for (int o = lane; o < CPW * 196; o += 64) {
        op0[o] = Ow[o];
    }
}

extern "C" void kernel_launch(void* const* d_in, const int* in_sizes, int n_in,
                              void* d_out, int out_size, void* d_ws, size_t ws_size,
                              hipStream_t stream) {
    const float* feat = (const float*)d_in[0];
    const float* rois = (const float*)d_in[1];
    float* out = (float*)d_out;
    const int grid = 256 * (C_ / CPB);   // 4096 blocks
    roi_mask_align_avg_kernel<<<grid, 256, 0, stream>>>(feat, rois, out);
}

// Round 5
// 275.831 us; speedup vs baseline: 1.0997x; 1.0130x over previous
//
#include <hip/hip_runtime.h>

// RoIMaskAlignAvg: features (B=2, C=256, H=200, W=272) fp32, rois (N=256, 5)
// -> out (256, 256, 14, 14) fp32.
// out[ah,aw] = sum over 4x4 window (stride 2) of a 30x30 bilinear sample grid,
// with the 1/16 scale folded into the bilinear weights (0.25 into wx, 0.25 into wy).
//
// Register pipeline (r3): lanes 0..31 sample row 2p, lanes 32..63 row 2p+1
// (ix = lane&31, samples 0..29 valid). Horizontal 4-window sums via
// shfl_xor(1)+shfl_down(2) (DPP-able); cross-half row-pair via shfl_xor(32);
// vertical 4-sum via prev-pass register. CPW=4 channels per wave share
// y-metadata/weights/gather-offsets.
//
// Stores (r4): staged in per-wave LDS, then one coalesced 64-lane pass over the
// wave's contiguous 4-channel 784-float span. Wave-synchronous, no barriers.
//
// r5 fixes L2 residency: 128-thread blocks (CPB=8) so each XCD's streamed
// working set is 8ch x 2batches x 217.6KB = 3.5MB < 4MB L2 (r4's 16ch = 7MB
// thrashed -> FETCH 130MB). Output stores are non-temporal so the 50MB of
// writes don't evict the resident feature slice.

#define C_  256
#define H_  200
#define W_  272
#define CPW 4          // channels per wave
#define WPB 2          // waves per block
#define CPB (CPW * WPB)  // 8 channels per block

__global__ __launch_bounds__(128)
void roi_mask_align_avg_kernel(const float* __restrict__ feat,
                               const float* __restrict__ rois,
                               float* __restrict__ out) {
    __shared__ float Obuf[WPB][CPW * 196];   // 2 waves * 784 floats = 6.27 KB

    const int tid  = threadIdx.x;
    const int wave = tid >> 6;
    const int lane = tid & 63;
    const int ix   = lane & 31;    // sample x index (0..29 used)
    const int half = lane >> 5;    // row parity within a pass

    // XCD-aware swizzle: XCD (p%8) streams a fixed 8-channel slice over all
    // rois before moving to the next slice (cgi-major outer).
    const int p   = blockIdx.x;                // grid = 8192
    const int xcd = p & 7;
    const int q   = p >> 3;
    const int n   = q & 255;
    const int cgi = q >> 8;                    // 0..3
    const int cg  = cgi * 8 + xcd;             // 0..31
    const int c0  = cg * CPB + wave * CPW;     // this wave's first channel

    // --- per-roi geometry (reference fp op order) ---
    const float r0f = rois[n * 5 + 0];
    const float x1s = rois[n * 5 + 1] * 0.25f;
    const float y1s = rois[n * 5 + 2] * 0.25f;
    const float x2s = rois[n * 5 + 3] * 0.25f;
    const float y2s = rois[n * 5 + 4] * 0.25f;
    const int   b   = (int)r0f;

    const float cx = 0.5f * (x1s + x2s), cy = 0.5f * (y1s + y2s);
    const float hw = 0.5f * (x2s - x1s), hh = 0.5f * (y2s - y1s);
    const float x1 = cx - hw, x2 = cx + hw;
    const float y1 = cy - hh, y2 = cy + hh;
    const float roi_w = fmaxf(x2 - x1, 1.0f);
    const float roi_h = fmaxf(y2 - y1, 1.0f);
    const float sub_w = roi_w * (1.0f / 15.0f) * 0.5f;
    const float sub_h = roi_h * (1.0f / 15.0f) * 0.5f;

    // --- x metadata in registers (1/4 of the 1/16 scale folded into wx) ---
    const float sx  = x1 + ((float)ix + 0.5f) * sub_w;
    const float vmx = ((sx > -1.0f) && (sx < (float)W_)) ? 0.25f : 0.0f;
    const float ccx = fminf(fmaxf(sx, 0.0f), (float)(W_ - 1));
    const float lox = floorf(ccx);
    const int   xl  = (int)lox;
    const int   xh  = min(xl + 1, W_ - 1);
    const float fxv = ccx - lox;
    const float wx0 = (1.0f - fxv) * vmx;
    const float wx1 = fxv * vmx;

    const size_t HW = (size_t)H_ * W_;
    const float* __restrict__ fp0 = feat + ((size_t)b * C_ + c0) * HW;

    const bool writer = (half == 0) && ((ix & 1) == 0) && (ix < 28);
    const int  ocol   = ix >> 1;           // aw
    float* __restrict__ Ow = Obuf[wave];

    float prev[CPW];
    #pragma unroll
    for (int k = 0; k < CPW; ++k) prev[k] = 0.0f;

    for (int ps = 0; ps < 15; ++ps) {
        // --- y metadata for this pass's row (shared across 4 channels) ---
        const int   iy  = 2 * ps + half;
        const float sy  = y1 + ((float)iy + 0.5f) * sub_h;
        const float vmy = ((sy > -1.0f) && (sy < (float)H_)) ? 0.25f : 0.0f;
        const float ccy = fminf(fmaxf(sy, 0.0f), (float)(H_ - 1));
        const float loy = floorf(ccy);
        const int   yl  = (int)loy;
        const int   yh  = min(yl + 1, H_ - 1);
        const float fyv = ccy - loy;
        const float wy0 = (1.0f - fyv) * vmy;
        const float wy1 = fyv * vmy;

        const float w00 = wy0 * wx0, w01 = wy0 * wx1;
        const float w10 = wy1 * wx0, w11 = wy1 * wx1;
        const int o00 = yl * W_ + xl, o01 = yl * W_ + xh;
        const int o10 = yh * W_ + xl, o11 = yh * W_ + xh;

        #pragma unroll
        for (int k = 0; k < CPW; ++k) {
            const float* __restrict__ fpk = fp0 + (size_t)k * HW;
            const float v = fpk[o00] * w00 + fpk[o01] * w01
                          + fpk[o10] * w10 + fpk[o11] * w11;
            // horizontal 4-window sum at even ix: v(ix)+..+v(ix+3)
            const float s1 = v  + __shfl_xor(v, 1);
            const float hs = s1 + __shfl_down(s1, 2);
            // vertical row-pair: row 2p + row 2p+1
            const float pr = hs + __shfl_xor(hs, 32);
            // out row (ps-1) = pair(ps-1) + pair(ps); stage in LDS
            if (ps > 0 && writer) {
                Ow[k * 196 + (ps - 1) * 14 + ocol] = prev[k] + pr;
            }
            prev[k] = pr;
        }
    }

    // --- coalesced non-temporal store: 4 consecutive channels contiguous ---
    // wave-synchronous (same wave wrote Ow) -> no barrier needed
    float* __restrict__ op0 = out + ((size_t)n * C_ + c0) * 196;
    #pragma unroll
    for (int o = lane; o < CPW * 196; o += 64) {
        __builtin_nontemporal_store(Ow[o], &op0[o]);
    }
}

extern "C" void kernel_launch(void* const* d_in, const int* in_sizes, int n_in,
                              void* d_out, int out_size, void* d_ws, size_t ws_size,
                              hipStream_t stream) {
    const float* feat = (const float*)d_in[0];
    const float* rois = (const float*)d_in[1];
    float* out = (float*)d_out;
    const int grid = 256 * (C_ / CPB);   // 8192 blocks
    roi_mask_align_avg_kernel<<<grid, 128, 0, stream>>>(feat, rois, out);
}